// Round 11
// baseline (414.281 us; speedup 1.0000x reference)
//
#include <hip/hip_runtime.h>
#include <hip/hip_bf16.h>

// GroupQuantLinear: y[m,n] = sum_k x[m,k]*(q[n,k]*s[n,g]+b[n,g]) + bias[n]
// M=4096, N=16384, K=4096, G=16.
//
// Round 11: i8 path v6 — 4-buffer rotation, ONE barrier per K-tile.
//   r6-r10 isolated the pin: the 2nd barrier per tile (compute-end ->
//   next overwrite) serializes staging against compute. 4 slots (BK=64,
//   32KB each) let tile t+3 stage into buf (t-1)&3 right AFTER the single
//   barrier: overwrite target was consumed at t-1 (all waves past it via
//   barrier), reads of tile t are safe via per-wave vmcnt(8) before the
//   barrier. Prefetch depth 2 tiles; vmcnt never 0 in loop.
//   Geometry/swizzle/quant/epilogue: r8/r10-validated (0 conflicts,
//   absmax 0.375).
// Fallbacks: r2 bf16-predecode 128^2 kernel; r1 fused kernel.

typedef short bf16x8 __attribute__((ext_vector_type(8)));
typedef float f32x4 __attribute__((ext_vector_type(4)));
typedef int i32x4 __attribute__((ext_vector_type(4)));
typedef unsigned short u16;
typedef unsigned short u16x8 __attribute__((ext_vector_type(8)));

#define BM 128
#define BN 128
#define BK 64
#define THREADS 256

static __device__ __forceinline__ u16 f2bf(float f) {
    __hip_bfloat16 h = __float2bfloat16(f);
    return __builtin_bit_cast(u16, h);
}

// ---------------- i8 precompute kernels (r6-r10 validated) ----------------

__global__ void rowstat_kernel(const float* __restrict__ x, float* __restrict__ sx,
                               float* __restrict__ rsx, int K) {
    const int m = blockIdx.x;
    const int l = threadIdx.x;  // 64
    const float4* p = (const float4*)(x + (size_t)m * K);
    float mx = 0.f;
    for (int i = l; i < (K >> 2); i += 64) {
        const float4 v = p[i];
        mx = fmaxf(mx, fmaxf(fmaxf(fabsf(v.x), fabsf(v.y)),
                             fmaxf(fabsf(v.z), fabsf(v.w))));
    }
    #pragma unroll
    for (int o = 32; o; o >>= 1) mx = fmaxf(mx, __shfl_xor(mx, o));
    if (l == 0) {
        mx = fmaxf(mx, 1e-20f);
        sx[m]  = mx * (1.f / 127.f);
        rsx[m] = 127.f / mx;
    }
}

__global__ void quantX_kernel(const float* __restrict__ x, const float* __restrict__ rsx,
                              char* __restrict__ xq, int kshift, size_t n16) {
    size_t i = (size_t)blockIdx.x * blockDim.x + threadIdx.x;
    if (i >= n16) return;
    const int m = (int)((i * 16) >> kshift);
    const float r = rsx[m];
    const float4* px = (const float4*)(x + i * 16);
    int out[4];
    #pragma unroll
    for (int w = 0; w < 4; ++w) {
        const float4 v = px[w];
        const int b0 = __float2int_rn(v.x * r) & 0xFF;
        const int b1 = __float2int_rn(v.y * r) & 0xFF;
        const int b2 = __float2int_rn(v.z * r) & 0xFF;
        const int b3 = __float2int_rn(v.w * r) & 0xFF;
        out[w] = b0 | (b1 << 8) | (b2 << 16) | (b3 << 24);
    }
    *(int4*)(xq + i * 16) = make_int4(out[0], out[1], out[2], out[3]);
}

__global__ void rowscaleW_kernel(const float* __restrict__ Ws,
                                 const float* __restrict__ Wb,
                                 float* __restrict__ swr, float* __restrict__ rswr,
                                 int G, int N) {
    const int n = blockIdx.x * blockDim.x + threadIdx.x;
    if (n >= N) return;
    float mx = 1e-20f;
    for (int g = 0; g < G; ++g) {
        const float s = Ws[(size_t)n * G + g];
        const float b = Wb[(size_t)n * G + g];
        mx = fmaxf(mx, fmaxf(fabsf(b), fabsf(fmaf(15.f, s, b))));
    }
    swr[n]  = mx * (1.f / 127.f);
    rswr[n] = 127.f / mx;
}

__global__ void quantW_row_kernel(const int* __restrict__ Wp, const float* __restrict__ Ws,
                                  const float* __restrict__ Wb, const float* __restrict__ rswr,
                                  char* __restrict__ wq, int K, int G, int gshift,
                                  int kcshift, size_t nthr) {
    size_t t = (size_t)blockIdx.x * blockDim.x + threadIdx.x;
    if (t >= nthr) return;
    const int n  = (int)(t >> kcshift);
    const int kc = (int)(t & ((1u << kcshift) - 1));
    const int g  = (kc << 4) >> gshift;
    const float s = Ws[(size_t)n * G + g];
    const float b = Wb[(size_t)n * G + g];
    const float rs = rswr[n];
    const int4 wv = *(const int4*)(Wp + (size_t)n * (K >> 2) + ((size_t)kc << 2));
    const int wds[4] = {wv.x, wv.y, wv.z, wv.w};
    int out[4];
    #pragma unroll
    for (int w = 0; w < 4; ++w) {
        int o = 0;
        #pragma unroll
        for (int j = 0; j < 4; ++j) {
            const float v = fmaf((float)((wds[w] >> (4 * j)) & 0xF), s, b);
            o |= (__float2int_rn(v * rs) & 0xFF) << (8 * j);
        }
        out[w] = o;
    }
    *(int4*)(wq + t * 16) = make_int4(out[0], out[1], out[2], out[3]);
}

// -- i8 GEMM: 256x256 block, 8 waves of 128x64, 16x16x64 MFMA, BK=64,
//    4-slot rotation, 1 barrier + 1 counted vmcnt per tile --

__global__ __launch_bounds__(512, 2)
void gql_gemm_i8q(const char* __restrict__ xq,   // [M][K] i8
                  const char* __restrict__ wq,   // [N][K] i8
                  const float* __restrict__ swr, // [N]
                  const float* __restrict__ sx,  // [M]
                  const float* __restrict__ Bias,
                  float* __restrict__ Out,       // [M][N] f32
                  int M, int N, int K)
{
    __shared__ __align__(16) char sA[4][256 * 64];  // 16 KB/slot
    __shared__ __align__(16) char sB[4][256 * 64];  // 16 KB/slot -> 128 KB

    const int tid  = threadIdx.x;
    const int lane = tid & 63;
    const int wid  = tid >> 6;     // 0..7
    const int wm   = wid >> 2;     // 0..1 -> rows wm*128
    const int wn   = wid & 3;      // 0..3 -> cols wn*64

    const int nwg = gridDim.x;
    int wg = blockIdx.x;
    if ((nwg & 7) == 0) wg = (wg & 7) * (nwg >> 3) + (wg >> 3);
    const int nt = N / 256;
    const int m0 = (wg / nt) * 256;
    const int n0 = (wg % nt) * 256;

    const int fr = lane & 15;   // fragment row lane
    const int fq = lane >> 4;   // 0..3 -> logical 16B k-chunk

    // staging (r10-validated, 0 conflicts): per inst 64 lanes x 16B =
    // 16 rows x 64B, linear LDS dest; source kc permuted (involution)
    // so the swizzled read recovers logical chunk fq.
    const int st_kc = ((lane & 3) ^ ((lane >> 3) & 3)) << 4;
    const int st_rw = lane >> 2;
    // read granule: q = fq ^ ((fr>>1)&3) -> 2-way per 16-lane quarter (free)
    const int rq = (fq ^ ((fr >> 1) & 3)) << 4;

    i32x4 acc[8][4] = {};

    const int NT = K >> 6;  // BK=64

    auto stage = [&](int t, int slot) {
        const size_t k0 = (size_t)t << 6;
        #pragma unroll
        for (int i = 0; i < 2; ++i) {              // A: 2 insts/wave
            const int inst = wid + i * 8;          // 0..15
            const int row  = inst * 16 + st_rw;    // 0..255
            const char* src = xq + (size_t)(m0 + row) * K + k0 + st_kc;
            __builtin_amdgcn_global_load_lds(
                (const __attribute__((address_space(1))) void*)src,
                (__attribute__((address_space(3))) void*)&sA[slot][inst * 1024],
                16, 0, 0);
        }
        #pragma unroll
        for (int i = 0; i < 2; ++i) {              // B: 2 insts/wave
            const int inst = wid + i * 8;          // 0..15
            const int row  = inst * 16 + st_rw;    // 0..255
            const char* src = wq + (size_t)(n0 + row) * K + k0 + st_kc;
            __builtin_amdgcn_global_load_lds(
                (const __attribute__((address_space(1))) void*)src,
                (__attribute__((address_space(3))) void*)&sB[slot][inst * 1024],
                16, 0, 0);
        }
    };

    auto compute = [&](int slot) {
        i32x4 af[8], bfr[4];
        #pragma unroll
        for (int i = 0; i < 8; ++i) {
            const int row = wm * 128 + i * 16 + fr;
            const u16x8 raw = *(const u16x8*)(&sA[slot][row * 64 + rq]);
            af[i] = __builtin_bit_cast(i32x4, raw);
        }
        #pragma unroll
        for (int j = 0; j < 4; ++j) {
            const int row = wn * 64 + j * 16 + fr;
            const u16x8 raw = *(const u16x8*)(&sB[slot][row * 64 + rq]);
            bfr[j] = __builtin_bit_cast(i32x4, raw);
        }
        __builtin_amdgcn_s_setprio(1);
        #pragma unroll
        for (int i = 0; i < 8; ++i)
            #pragma unroll
            for (int j = 0; j < 4; ++j)
                acc[i][j] = __builtin_amdgcn_mfma_i32_16x16x64_i8(
                    af[i], bfr[j], acc[i][j], 0, 0, 0);
        __builtin_amdgcn_s_setprio(0);
    };

    // prologue: 3 tiles in flight (12 loads/wave)
    stage(0, 0); stage(1, 1); stage(2, 2);

    for (int t = 0; t < NT; ++t) {
        // tile t landed; t+1,t+2 (8 loads) stay in flight across the barrier
        asm volatile("s_waitcnt vmcnt(8)" ::: "memory");
        __builtin_amdgcn_sched_barrier(0);
        __builtin_amdgcn_s_barrier();          // the ONLY barrier this tile
        asm volatile("" ::: "memory");
        // stage t+3 into slot (t+3)&3 == (t-1)&3: consumed at t-1, and the
        // barrier above is ordered after every wave's compute(t-1).
        const int tn = (t + 3 < NT) ? (t + 3) : (NT - 1);  // clamp: dead slot
        stage(tn, (t + 3) & 3);
        compute(t & 3);
    }

    asm volatile("s_waitcnt vmcnt(0)" ::: "memory");  // drain tail stages

    // epilogue: 16x16 C-layout (validated): col = fr, row = 4*fq + reg
    #pragma unroll
    for (int j = 0; j < 4; ++j) {
        const int col = n0 + wn * 64 + j * 16 + fr;
        const float bv = Bias[col];
        const float sv = swr[col];
        #pragma unroll
        for (int i = 0; i < 8; ++i) {
            const int mb = m0 + wm * 128 + i * 16 + (fq << 2);
            #pragma unroll
            for (int r = 0; r < 4; ++r)
                Out[(size_t)(mb + r) * N + col] =
                    fmaf(sx[mb + r] * sv, (float)acc[i][j][r], bv);
        }
    }
}

// ---------------- bf16 predecode kernels (fallback path) ----------------

__global__ void cvtA_kernel(const float* __restrict__ A, u16* __restrict__ wsA,
                            size_t n8) {
    size_t i = (size_t)blockIdx.x * blockDim.x + threadIdx.x;
    if (i >= n8) return;
    const float4 v0 = *(const float4*)(A + i * 8);
    const float4 v1 = *(const float4*)(A + i * 8 + 4);
    u16x8 h;
    h[0] = f2bf(v0.x); h[1] = f2bf(v0.y); h[2] = f2bf(v0.z); h[3] = f2bf(v0.w);
    h[4] = f2bf(v1.x); h[5] = f2bf(v1.y); h[6] = f2bf(v1.z); h[7] = f2bf(v1.w);
    *(u16x8*)(wsA + i * 8) = h;
}

__global__ void deqW_kernel(const int* __restrict__ Wp, const float* __restrict__ Ws,
                            const float* __restrict__ Wb, u16* __restrict__ wsW,
                            int K, int G, int gshift, int kgshift, size_t n8) {
    size_t t = (size_t)blockIdx.x * blockDim.x + threadIdx.x;
    if (t >= n8) return;
    const int n  = (int)(t >> kgshift);
    const int kg = (int)(t & ((1u << kgshift) - 1));
    const int k  = kg << 3;
    const int g  = k >> gshift;
    const float s = Ws[n * G + g];
    const float b = Wb[n * G + g];
    const int2 w2 = *(const int2*)(Wp + (size_t)n * (K >> 2) + (k >> 2));
    u16x8 h;
    #pragma unroll
    for (int j = 0; j < 4; ++j)
        h[j]     = f2bf(fmaf((float)((w2.x >> (4 * j)) & 0xF), s, b));
    #pragma unroll
    for (int j = 0; j < 4; ++j)
        h[4 + j] = f2bf(fmaf((float)((w2.y >> (4 * j)) & 0xF), s, b));
    *(u16x8*)(wsW + ((size_t)n << (kgshift + 3)) + k) = h;
}

__global__ __launch_bounds__(THREADS, 2)
void gql_gemm_pre(const u16* __restrict__ wsA,
                  const u16* __restrict__ wsW,
                  const float* __restrict__ Bias,
                  float* __restrict__ Out,
                  int M, int N, int K)
{
    __shared__ __align__(16) u16 sA[BM * BK];
    __shared__ __align__(16) u16 sB[BN * BK];

    const int tid  = threadIdx.x;
    const int lane = tid & 63;
    const int wid  = tid >> 6;

    const int nwg = gridDim.x;
    int wg = blockIdx.x;
    if ((nwg & 7) == 0) wg = (wg & 7) * (nwg >> 3) + (wg >> 3);
    const int nt     = N / BN;
    const int m0 = (wg / nt) * BM;
    const int n0 = (wg % nt) * BN;

    const int st_r  = (lane >> 3);
    const int st_g  = lane & 7;

    const int wr = (wid >> 1) << 6;
    const int wc = (wid & 1) << 6;
    const int fr = lane & 15;
    const int fq = lane >> 4;

    f32x4 acc[4][4] = {};

    for (int k0 = 0; k0 < K; k0 += BK) {
        __syncthreads();

        #pragma unroll
        for (int i = 0; i < 4; ++i) {
            const int r = wid * 32 + i * 8 + st_r;
            const int gsrc = (st_g ^ (r & 7)) << 3;
            const u16* srcA = wsA + (size_t)(m0 + r) * K + k0 + gsrc;
            const u16* srcB = wsW + (size_t)(n0 + r) * K + k0 + gsrc;
            __builtin_amdgcn_global_load_lds(
                (const __attribute__((address_space(1))) void*)srcA,
                (__attribute__((address_space(3))) void*)&sA[(wid * 32 + i * 8) * BK],
                16, 0, 0);
            __builtin_amdgcn_global_load_lds(
                (const __attribute__((address_space(1))) void*)srcB,
                (__attribute__((address_space(3))) void*)&sB[(wid * 32 + i * 8) * BK],
                16, 0, 0);
        }

        __syncthreads();

        #pragma unroll
        for (int sub = 0; sub < 2; ++sub) {
            const int kch = (sub << 2) + fq;
            bf16x8 af[4], bfg[4];
            #pragma unroll
            for (int i = 0; i < 4; ++i) {
                const int row = wr + i * 16 + fr;
                af[i] = *(const bf16x8*)((const char*)sA + row * (BK * 2)
                                         + (((kch ^ (row & 7)) << 4)));
            }
            #pragma unroll
            for (int j = 0; j < 4; ++j) {
                const int row = wc + j * 16 + fr;
                bfg[j] = *(const bf16x8*)((const char*)sB + row * (BK * 2)
                                          + (((kch ^ (row & 7)) << 4)));
            }
            #pragma unroll
            for (int i = 0; i < 4; ++i)
                #pragma unroll
                for (int j = 0; j < 4; ++j)
                    acc[i][j] = __builtin_amdgcn_mfma_f32_16x16x32_bf16(
                        af[i], bfg[j], acc[i][j], 0, 0, 0);
        }
    }

    #pragma unroll
    for (int j = 0; j < 4; ++j) {
        const int n = n0 + wc + j * 16 + fr;
        const float bvv = Bias[n];
        #pragma unroll
        for (int i = 0; i < 4; ++i) {
            const int mb = m0 + wr + i * 16 + (fq << 2);
            #pragma unroll
            for (int r = 0; r < 4; ++r)
                Out[(size_t)(mb + r) * N + n] = acc[i][j][r] + bvv;
        }
    }
}

// ---------------- round-1 fused fallback ----------------

__global__ __launch_bounds__(THREADS, 2)
void gql_gemm(const float* __restrict__ A,
              const int* __restrict__ Wp,
              const float* __restrict__ Ws,
              const float* __restrict__ Wb,
              const float* __restrict__ Bias,
              float* __restrict__ Out,
              int M, int N, int K, int G, int gshift)
{
    __shared__ __align__(16) u16 sA[BM * BK];
    __shared__ __align__(16) u16 sB[BN * BK];

    const int tid  = threadIdx.x;
    const int lane = tid & 63;
    const int wid  = tid >> 6;

    const int nwg = gridDim.x;
    int wg = blockIdx.x;
    if ((nwg & 7) == 0) wg = (wg & 7) * (nwg >> 3) + (wg >> 3);
    const int nt     = N / BN;
    const int m0 = (wg / nt) * BM;
    const int n0 = (wg % nt) * BN;

    const int wpr = K >> 2;

    const int a_r = tid >> 4;
    const int a_c = (tid & 15) << 2;
    const int b_r = tid >> 3;
    const int b_w = (tid & 7) << 1;

    const int wr = (wid >> 1) << 6;
    const int wc = (wid & 1) << 6;
    const int fr = lane & 15;
    const int fq = lane >> 4;

    f32x4 acc[4][4] = {};

    for (int k0 = 0; k0 < K; k0 += BK) {
        __syncthreads();

        #pragma unroll
        for (int it = 0; it < 8; ++it) {
            const int row = it * 16 + a_r;
            const float4 v = *(const float4*)(A + (size_t)(m0 + row) * K + (k0 + a_c));
            u16 h0 = f2bf(v.x), h1 = f2bf(v.y), h2 = f2bf(v.z), h3 = f2bf(v.w);
            const int byte = (a_c << 1) ^ ((row & 7) << 4);
            *(u16*)((char*)sA + row * (BK * 2) + byte + 0) = h0;
            *(u16*)((char*)sA + row * (BK * 2) + byte + 2) = h1;
            *(u16*)((char*)sA + row * (BK * 2) + byte + 4) = h2;
            *(u16*)((char*)sA + row * (BK * 2) + byte + 6) = h3;
        }

        const int g = k0 >> gshift;
        #pragma unroll
        for (int it = 0; it < 4; ++it) {
            const int row = it * 32 + b_r;
            const int gn  = n0 + row;
            const int2 w2 = *(const int2*)(Wp + (size_t)gn * wpr + (k0 >> 2) + b_w);
            const float s = Ws[gn * G + g];
            const float b = Wb[gn * G + g];
            u16x8 h;
            #pragma unroll
            for (int j = 0; j < 4; ++j)
                h[j]     = f2bf(fmaf((float)((w2.x >> (4 * j)) & 0xF), s, b));
            #pragma unroll
            for (int j = 0; j < 4; ++j)
                h[4 + j] = f2bf(fmaf((float)((w2.y >> (4 * j)) & 0xF), s, b));
            const int byte = (b_w << 3) ^ ((row & 7) << 4);
            *(u16x8*)((char*)sB + row * (BK * 2) + byte) = h;
        }

        __syncthreads();

        #pragma unroll
        for (int sub = 0; sub < 2; ++sub) {
            const int kch = (sub << 2) + fq;
            bf16x8 af[4], bfg[4];
            #pragma unroll
            for (int i = 0; i < 4; ++i) {
                const int row = wr + i * 16 + fr;
                af[i] = *(const bf16x8*)((const char*)sA + row * (BK * 2)
                                         + ((kch << 4) ^ ((row & 7) << 4)));
            }
            #pragma unroll
            for (int j = 0; j < 4; ++j) {
                const int row = wc + j * 16 + fr;
                bfg[j] = *(const bf16x8*)((const char*)sB + row * (BK * 2)
                                          + ((kch << 4) ^ ((row & 7) << 4)));
            }
            #pragma unroll
            for (int i = 0; i < 4; ++i)
                #pragma unroll
                for (int j = 0; j < 4; ++j)
                    acc[i][j] = __builtin_amdgcn_mfma_f32_16x16x32_bf16(
                        af[i], bfg[j], acc[i][j], 0, 0, 0);
        }
    }

    #pragma unroll
    for (int j = 0; j < 4; ++j) {
        const int n = n0 + wc + j * 16 + fr;
        const float bvv = Bias[n];
        #pragma unroll
        for (int i = 0; i < 4; ++i) {
            const int mb = m0 + wr + i * 16 + (fq << 2);
            #pragma unroll
            for (int r = 0; r < 4; ++r)
                Out[(size_t)(mb + r) * N + n] = acc[i][j][r] + bvv;
        }
    }
}

extern "C" void kernel_launch(void* const* d_in, const int* in_sizes, int n_in,
                              void* d_out, int out_size, void* d_ws, size_t ws_size,
                              hipStream_t stream) {
    const float* A    = (const float*)d_in[0];
    const int*   Wp   = (const int*)d_in[1];
    const float* Ws   = (const float*)d_in[2];
    const float* Wb   = (const float*)d_in[3];
    const float* Bias = (const float*)d_in[4];
    float* Out = (float*)d_out;

    const int OUT  = in_sizes[4];
    const int OG   = in_sizes[2];          // OUT * G
    const int G    = OG / OUT;             // 16
    const int cols = in_sizes[1] / OG;     // 64
    const int IN   = G * cols * 4;         // 4096
    const int M    = in_sizes[0] / IN;     // 4096

    const int gk = IN / G;                 // 256
    int gshift = 0;
    while ((1 << gshift) < gk) ++gshift;   // 8

    int kshift = 0;
    while ((1 << kshift) < IN) ++kshift;   // 12

    const size_t needXq = (size_t)M * IN;
    const size_t needWq = (size_t)OUT * IN;
    const size_t needSc = (size_t)M * 8 + (size_t)OUT * 8;
    const size_t needI8 = needXq + needWq + needSc;

    const bool kpow2  = ((IN & (IN - 1)) == 0);
    const bool gkpow2 = ((1 << gshift) == gk);

    if (ws_size >= needI8 && kpow2 && gkpow2 && (IN % 256) == 0 &&
        (M % 256) == 0 && (OUT % 256) == 0 && (gk % 16) == 0) {
        char*  xq   = (char*)d_ws;
        char*  wq   = (char*)d_ws + needXq;
        float* sx   = (float*)((char*)d_ws + needXq + needWq);
        float* rsx  = sx + M;
        float* swr  = rsx + M;
        float* rswr = swr + OUT;

        rowstat_kernel<<<M, 64, 0, stream>>>(A, sx, rsx, IN);

        const size_t n16 = (size_t)M * IN / 16;
        quantX_kernel<<<(unsigned)((n16 + 255) / 256), 256, 0, stream>>>(
            A, rsx, xq, kshift, n16);

        rowscaleW_kernel<<<(OUT + 255) / 256, 256, 0, stream>>>(Ws, Wb, swr, rswr,
                                                                G, OUT);

        const int kcshift = kshift - 4;                 // log2(K/16)
        const size_t nthr = (size_t)OUT * (IN >> 4);
        quantW_row_kernel<<<(unsigned)((nthr + 255) / 256), 256, 0, stream>>>(
            Wp, Ws, Wb, rswr, wq, IN, G, gshift, kcshift, nthr);

        dim3 grid((M / 256) * (OUT / 256));
        gql_gemm_i8q<<<grid, 512, 0, stream>>>(xq, wq, swr, sx, Bias, Out,
                                               M, OUT, IN);
        return;
    }

    const size_t needA = (size_t)M * IN * 2;
    const size_t needW = (size_t)OUT * IN * 2;

    if (ws_size >= needA + needW && (IN & 7) == 0 &&
        (M % 128) == 0 && (OUT % 128) == 0 && (IN % 64) == 0) {
        u16* wsA = (u16*)d_ws;
        u16* wsW = (u16*)((char*)d_ws + needA);

        const size_t nA8 = (size_t)M * IN / 8;
        cvtA_kernel<<<(unsigned)((nA8 + 255) / 256), 256, 0, stream>>>(A, wsA, nA8);

        int kgshift = 0;
        while ((1 << kgshift) < (IN >> 3)) ++kgshift;
        const size_t nW8 = (size_t)OUT * IN / 8;
        deqW_kernel<<<(unsigned)((nW8 + 255) / 256), 256, 0, stream>>>(
            Wp, Ws, Wb, wsW, IN, G, gshift, kgshift, nW8);

        dim3 grid((M / BM) * (OUT / BN));
        gql_gemm_pre<<<grid, THREADS, 0, stream>>>(wsA, wsW, Bias, Out, M, OUT, IN);
    } else {
        dim3 grid((M / BM) * (OUT / BN));
        gql_gemm<<<grid, THREADS, 0, stream>>>(A, Wp, Ws, Wb, Bias, Out,
                                               M, OUT, IN, G, gshift);
    }
}

// Round 12
// 409.329 us; speedup vs baseline: 1.0121x; 1.0121x over previous
//
#include <hip/hip_runtime.h>
#include <hip/hip_bf16.h>

// GroupQuantLinear: y[m,n] = sum_k x[m,k]*(q[n,k]*s[n,g]+b[n,g]) + bias[n]
// M=4096, N=16384, K=4096, G=16.
//
// Round 12: i8 path v7 — faithful m201-style 8-phase schedule.
//   Iter = 2 K-tiles (BK=128). buf0=even tiles, buf1=odd (static indices).
//   8 phases x 16 MFMA (quadrant = kc x mi-half). Per phase:
//   {ds_reads | stage(ph1/2/5/6: 4 DMA) -> lgkmcnt(0)+sched_barrier ->
//    setprio(1) 16xMFMA setprio(0) -> barrier}. Counted waits only at
//   ph1 (buf0, staged prev ph5/6) and ph5 (buf1, staged ph1/2): each
//   drains exactly the 8 loads it needs; stages fly >=3 phases.
//   Swizzle/quant/epilogue: r8-validated (0 conflicts, absmax 0.375).
// Fallbacks: r2 bf16-predecode 128^2 kernel; r1 fused kernel.

typedef short bf16x8 __attribute__((ext_vector_type(8)));
typedef float f32x4 __attribute__((ext_vector_type(4)));
typedef int i32x4 __attribute__((ext_vector_type(4)));
typedef unsigned short u16;
typedef unsigned short u16x8 __attribute__((ext_vector_type(8)));

#define BM 128
#define BN 128
#define BK 64
#define THREADS 256

static __device__ __forceinline__ u16 f2bf(float f) {
    __hip_bfloat16 h = __float2bfloat16(f);
    return __builtin_bit_cast(u16, h);
}

// ---------------- i8 precompute kernels (r6-r11 validated) ----------------

__global__ void rowstat_kernel(const float* __restrict__ x, float* __restrict__ sx,
                               float* __restrict__ rsx, int K) {
    const int m = blockIdx.x;
    const int l = threadIdx.x;  // 64
    const float4* p = (const float4*)(x + (size_t)m * K);
    float mx = 0.f;
    for (int i = l; i < (K >> 2); i += 64) {
        const float4 v = p[i];
        mx = fmaxf(mx, fmaxf(fmaxf(fabsf(v.x), fabsf(v.y)),
                             fmaxf(fabsf(v.z), fabsf(v.w))));
    }
    #pragma unroll
    for (int o = 32; o; o >>= 1) mx = fmaxf(mx, __shfl_xor(mx, o));
    if (l == 0) {
        mx = fmaxf(mx, 1e-20f);
        sx[m]  = mx * (1.f / 127.f);
        rsx[m] = 127.f / mx;
    }
}

__global__ void quantX_kernel(const float* __restrict__ x, const float* __restrict__ rsx,
                              char* __restrict__ xq, int kshift, size_t n16) {
    size_t i = (size_t)blockIdx.x * blockDim.x + threadIdx.x;
    if (i >= n16) return;
    const int m = (int)((i * 16) >> kshift);
    const float r = rsx[m];
    const float4* px = (const float4*)(x + i * 16);
    int out[4];
    #pragma unroll
    for (int w = 0; w < 4; ++w) {
        const float4 v = px[w];
        const int b0 = __float2int_rn(v.x * r) & 0xFF;
        const int b1 = __float2int_rn(v.y * r) & 0xFF;
        const int b2 = __float2int_rn(v.z * r) & 0xFF;
        const int b3 = __float2int_rn(v.w * r) & 0xFF;
        out[w] = b0 | (b1 << 8) | (b2 << 16) | (b3 << 24);
    }
    *(int4*)(xq + i * 16) = make_int4(out[0], out[1], out[2], out[3]);
}

__global__ void rowscaleW_kernel(const float* __restrict__ Ws,
                                 const float* __restrict__ Wb,
                                 float* __restrict__ swr, float* __restrict__ rswr,
                                 int G, int N) {
    const int n = blockIdx.x * blockDim.x + threadIdx.x;
    if (n >= N) return;
    float mx = 1e-20f;
    for (int g = 0; g < G; ++g) {
        const float s = Ws[(size_t)n * G + g];
        const float b = Wb[(size_t)n * G + g];
        mx = fmaxf(mx, fmaxf(fabsf(b), fabsf(fmaf(15.f, s, b))));
    }
    swr[n]  = mx * (1.f / 127.f);
    rswr[n] = 127.f / mx;
}

__global__ void quantW_row_kernel(const int* __restrict__ Wp, const float* __restrict__ Ws,
                                  const float* __restrict__ Wb, const float* __restrict__ rswr,
                                  char* __restrict__ wq, int K, int G, int gshift,
                                  int kcshift, size_t nthr) {
    size_t t = (size_t)blockIdx.x * blockDim.x + threadIdx.x;
    if (t >= nthr) return;
    const int n  = (int)(t >> kcshift);
    const int kc = (int)(t & ((1u << kcshift) - 1));
    const int g  = (kc << 4) >> gshift;
    const float s = Ws[(size_t)n * G + g];
    const float b = Wb[(size_t)n * G + g];
    const float rs = rswr[n];
    const int4 wv = *(const int4*)(Wp + (size_t)n * (K >> 2) + ((size_t)kc << 2));
    const int wds[4] = {wv.x, wv.y, wv.z, wv.w};
    int out[4];
    #pragma unroll
    for (int w = 0; w < 4; ++w) {
        int o = 0;
        #pragma unroll
        for (int j = 0; j < 4; ++j) {
            const float v = fmaf((float)((wds[w] >> (4 * j)) & 0xF), s, b);
            o |= (__float2int_rn(v * rs) & 0xFF) << (8 * j);
        }
        out[w] = o;
    }
    *(int4*)(wq + t * 16) = make_int4(out[0], out[1], out[2], out[3]);
}

// ---- i8 GEMM: 256x256, 8 waves of 128x64, BK=128, 8-phase schedule ----

#define LGKM0() do { asm volatile("s_waitcnt lgkmcnt(0)" ::: "memory"); \
                     __builtin_amdgcn_sched_barrier(0); } while (0)
#define BARRIER() do { __builtin_amdgcn_s_barrier(); \
                       asm volatile("" ::: "memory"); } while (0)

__global__ __launch_bounds__(512, 2)
void gql_gemm_i8v(const char* __restrict__ xq,   // [M][K] i8
                  const char* __restrict__ wq,   // [N][K] i8
                  const float* __restrict__ swr, // [N]
                  const float* __restrict__ sx,  // [M]
                  const float* __restrict__ Bias,
                  float* __restrict__ Out,       // [M][N] f32
                  int M, int N, int K)
{
    __shared__ __align__(16) char sA[2][256 * 128];  // 32 KB each
    __shared__ __align__(16) char sB[2][256 * 128];  // 32 KB each -> 128 KB

    const int tid  = threadIdx.x;
    const int lane = tid & 63;
    const int wid  = tid >> 6;     // 0..7
    const int wm   = wid >> 2;     // 0..1 -> rows wm*128
    const int wn   = wid & 3;      // 0..3 -> cols wn*64

    const int nwg = gridDim.x;
    int wg = blockIdx.x;
    if ((nwg & 7) == 0) wg = (wg & 7) * (nwg >> 3) + (wg >> 3);
    const int nt = N / 256;
    const int m0 = (wg / nt) * 256;
    const int n0 = (wg % nt) * 256;

    const int fr = lane & 15;
    const int fq = lane >> 4;

    // r8-validated staging (linear DMA dest, pre-swizzled source, 0 conflicts)
    const int st_row = lane >> 3;
    const int st_g   = ((lane & 7) ^ (lane >> 3)) << 4;

    i32x4 acc[8][4] = {};

    const int NT = K >> 7;   // BK=128 tiles
    const int NI = NT >> 1;  // iterations (2 tiles each)

    // half h (insts 2h,2h+1) of tile t -> buffer buf : 4 DMA insts/wave
    auto stage_half = [&](int t, int buf, int h) {
        const size_t k0 = (size_t)t << 7;
        #pragma unroll
        for (int i = h * 2; i < h * 2 + 2; ++i) {
            const int r = wid * 32 + i * 8 + st_row;
            const char* srcA = xq + (size_t)(m0 + r) * K + k0 + st_g;
            __builtin_amdgcn_global_load_lds(
                (const __attribute__((address_space(1))) void*)srcA,
                (__attribute__((address_space(3))) void*)&sA[buf][(wid * 32 + i * 8) * 128],
                16, 0, 0);
            const char* srcB = wq + (size_t)(n0 + r) * K + k0 + st_g;
            __builtin_amdgcn_global_load_lds(
                (const __attribute__((address_space(1))) void*)srcB,
                (__attribute__((address_space(3))) void*)&sB[buf][(wid * 32 + i * 8) * 128],
                16, 0, 0);
        }
    };

    // quadrant reads: af (4 rows of mi-half ih) + optionally bfr (kc chunk)
    auto rd = [&](const char* bA, const char* bB, int kk, int ih,
                  i32x4* af, i32x4* bfr, bool loadB) {
        const int gr = (((kk << 2) + fq) ^ (fr & 7)) << 4;
        #pragma unroll
        for (int i = 0; i < 4; ++i) {
            const int row = wm * 128 + (ih * 4 + i) * 16 + fr;
            af[i] = __builtin_bit_cast(i32x4, *(const u16x8*)(bA + row * 128 + gr));
        }
        if (loadB) {
            #pragma unroll
            for (int j = 0; j < 4; ++j) {
                const int row = wn * 64 + j * 16 + fr;
                bfr[j] = __builtin_bit_cast(i32x4, *(const u16x8*)(bB + row * 128 + gr));
            }
        }
    };

    const char* bA0 = &sA[0][0]; const char* bB0 = &sB[0][0];
    const char* bA1 = &sA[1][0]; const char* bB1 = &sB[1][0];

    // prologue: tile 0 -> buf0 (8 insts/wave outstanding)
    stage_half(0, 0, 0); stage_half(0, 0, 1);

    for (int u = 0; u < NI; ++u) {
        const int t1  = 2 * u + 1;                       // odd tile -> buf1
        const int tn0 = (2 * u + 2 < NT) ? 2 * u + 2 : NT - 1;  // next even (clamp dead)
        i32x4 af[4], bfr[4];

        // ---- ph1: publish buf0; stage buf1 h0; quadrant (kc0, ih0) ----
        asm volatile("s_waitcnt vmcnt(0)" ::: "memory");   // = exactly buf0's 8
        __builtin_amdgcn_sched_barrier(0);
        BARRIER();
        stage_half(t1, 1, 0);
        rd(bA0, bB0, 0, 0, af, bfr, true);
        LGKM0();
        __builtin_amdgcn_s_setprio(1);
        #pragma unroll
        for (int i = 0; i < 4; ++i)
            #pragma unroll
            for (int j = 0; j < 4; ++j)
                acc[i][j] = __builtin_amdgcn_mfma_i32_16x16x64_i8(af[i], bfr[j], acc[i][j], 0, 0, 0);
        __builtin_amdgcn_s_setprio(0);
        BARRIER();

        // ---- ph2: stage buf1 h1; (kc0, ih1) ----
        stage_half(t1, 1, 1);
        rd(bA0, bB0, 0, 1, af, bfr, false);
        LGKM0();
        __builtin_amdgcn_s_setprio(1);
        #pragma unroll
        for (int i = 0; i < 4; ++i)
            #pragma unroll
            for (int j = 0; j < 4; ++j)
                acc[4 + i][j] = __builtin_amdgcn_mfma_i32_16x16x64_i8(af[i], bfr[j], acc[4 + i][j], 0, 0, 0);
        __builtin_amdgcn_s_setprio(0);
        BARRIER();

        // ---- ph3: (kc1, ih0) ----
        rd(bA0, bB0, 1, 0, af, bfr, true);
        LGKM0();
        __builtin_amdgcn_s_setprio(1);
        #pragma unroll
        for (int i = 0; i < 4; ++i)
            #pragma unroll
            for (int j = 0; j < 4; ++j)
                acc[i][j] = __builtin_amdgcn_mfma_i32_16x16x64_i8(af[i], bfr[j], acc[i][j], 0, 0, 0);
        __builtin_amdgcn_s_setprio(0);
        BARRIER();

        // ---- ph4: (kc1, ih1) ----
        rd(bA0, bB0, 1, 1, af, bfr, false);
        LGKM0();
        __builtin_amdgcn_s_setprio(1);
        #pragma unroll
        for (int i = 0; i < 4; ++i)
            #pragma unroll
            for (int j = 0; j < 4; ++j)
                acc[4 + i][j] = __builtin_amdgcn_mfma_i32_16x16x64_i8(af[i], bfr[j], acc[4 + i][j], 0, 0, 0);
        __builtin_amdgcn_s_setprio(0);
        BARRIER();

        // ---- ph5: publish buf1; stage buf0 h0 (tile tn0); (kc0, ih0) ----
        asm volatile("s_waitcnt vmcnt(0)" ::: "memory");   // = exactly buf1's 8
        __builtin_amdgcn_sched_barrier(0);
        BARRIER();
        stage_half(tn0, 0, 0);
        rd(bA1, bB1, 0, 0, af, bfr, true);
        LGKM0();
        __builtin_amdgcn_s_setprio(1);
        #pragma unroll
        for (int i = 0; i < 4; ++i)
            #pragma unroll
            for (int j = 0; j < 4; ++j)
                acc[i][j] = __builtin_amdgcn_mfma_i32_16x16x64_i8(af[i], bfr[j], acc[i][j], 0, 0, 0);
        __builtin_amdgcn_s_setprio(0);
        BARRIER();

        // ---- ph6: stage buf0 h1; (kc0, ih1) ----
        stage_half(tn0, 0, 1);
        rd(bA1, bB1, 0, 1, af, bfr, false);
        LGKM0();
        __builtin_amdgcn_s_setprio(1);
        #pragma unroll
        for (int i = 0; i < 4; ++i)
            #pragma unroll
            for (int j = 0; j < 4; ++j)
                acc[4 + i][j] = __builtin_amdgcn_mfma_i32_16x16x64_i8(af[i], bfr[j], acc[4 + i][j], 0, 0, 0);
        __builtin_amdgcn_s_setprio(0);
        BARRIER();

        // ---- ph7: (kc1, ih0) ----
        rd(bA1, bB1, 1, 0, af, bfr, true);
        LGKM0();
        __builtin_amdgcn_s_setprio(1);
        #pragma unroll
        for (int i = 0; i < 4; ++i)
            #pragma unroll
            for (int j = 0; j < 4; ++j)
                acc[i][j] = __builtin_amdgcn_mfma_i32_16x16x64_i8(af[i], bfr[j], acc[i][j], 0, 0, 0);
        __builtin_amdgcn_s_setprio(0);
        BARRIER();

        // ---- ph8: (kc1, ih1) ----
        rd(bA1, bB1, 1, 1, af, bfr, false);
        LGKM0();
        __builtin_amdgcn_s_setprio(1);
        #pragma unroll
        for (int i = 0; i < 4; ++i)
            #pragma unroll
            for (int j = 0; j < 4; ++j)
                acc[4 + i][j] = __builtin_amdgcn_mfma_i32_16x16x64_i8(af[i], bfr[j], acc[4 + i][j], 0, 0, 0);
        __builtin_amdgcn_s_setprio(0);
        BARRIER();
    }

    asm volatile("s_waitcnt vmcnt(0)" ::: "memory");  // drain clamped tail stages

    // epilogue: 16x16 C-layout (validated): col = fr, row = 4*fq + reg
    #pragma unroll
    for (int j = 0; j < 4; ++j) {
        const int col = n0 + wn * 64 + j * 16 + fr;
        const float bv = Bias[col];
        const float sv = swr[col];
        #pragma unroll
        for (int i = 0; i < 8; ++i) {
            const int mb = m0 + wm * 128 + i * 16 + (fq << 2);
            #pragma unroll
            for (int r = 0; r < 4; ++r)
                Out[(size_t)(mb + r) * N + col] =
                    fmaf(sx[mb + r] * sv, (float)acc[i][j][r], bv);
        }
    }
}

// ---------------- bf16 predecode kernels (fallback path) ----------------

__global__ void cvtA_kernel(const float* __restrict__ A, u16* __restrict__ wsA,
                            size_t n8) {
    size_t i = (size_t)blockIdx.x * blockDim.x + threadIdx.x;
    if (i >= n8) return;
    const float4 v0 = *(const float4*)(A + i * 8);
    const float4 v1 = *(const float4*)(A + i * 8 + 4);
    u16x8 h;
    h[0] = f2bf(v0.x); h[1] = f2bf(v0.y); h[2] = f2bf(v0.z); h[3] = f2bf(v0.w);
    h[4] = f2bf(v1.x); h[5] = f2bf(v1.y); h[6] = f2bf(v1.z); h[7] = f2bf(v1.w);
    *(u16x8*)(wsA + i * 8) = h;
}

__global__ void deqW_kernel(const int* __restrict__ Wp, const float* __restrict__ Ws,
                            const float* __restrict__ Wb, u16* __restrict__ wsW,
                            int K, int G, int gshift, int kgshift, size_t n8) {
    size_t t = (size_t)blockIdx.x * blockDim.x + threadIdx.x;
    if (t >= n8) return;
    const int n  = (int)(t >> kgshift);
    const int kg = (int)(t & ((1u << kgshift) - 1));
    const int k  = kg << 3;
    const int g  = k >> gshift;
    const float s = Ws[n * G + g];
    const float b = Wb[n * G + g];
    const int2 w2 = *(const int2*)(Wp + (size_t)n * (K >> 2) + (k >> 2));
    u16x8 h;
    #pragma unroll
    for (int j = 0; j < 4; ++j)
        h[j]     = f2bf(fmaf((float)((w2.x >> (4 * j)) & 0xF), s, b));
    #pragma unroll
    for (int j = 0; j < 4; ++j)
        h[4 + j] = f2bf(fmaf((float)((w2.y >> (4 * j)) & 0xF), s, b));
    *(u16x8*)(wsW + ((size_t)n << (kgshift + 3)) + k) = h;
}

__global__ __launch_bounds__(THREADS, 2)
void gql_gemm_pre(const u16* __restrict__ wsA,
                  const u16* __restrict__ wsW,
                  const float* __restrict__ Bias,
                  float* __restrict__ Out,
                  int M, int N, int K)
{
    __shared__ __align__(16) u16 sA[BM * BK];
    __shared__ __align__(16) u16 sB[BN * BK];

    const int tid  = threadIdx.x;
    const int lane = tid & 63;
    const int wid  = tid >> 6;

    const int nwg = gridDim.x;
    int wg = blockIdx.x;
    if ((nwg & 7) == 0) wg = (wg & 7) * (nwg >> 3) + (wg >> 3);
    const int nt     = N / BN;
    const int m0 = (wg / nt) * BM;
    const int n0 = (wg % nt) * BN;

    const int st_r  = (lane >> 3);
    const int st_g  = lane & 7;

    const int wr = (wid >> 1) << 6;
    const int wc = (wid & 1) << 6;
    const int fr = lane & 15;
    const int fq = lane >> 4;

    f32x4 acc[4][4] = {};

    for (int k0 = 0; k0 < K; k0 += BK) {
        __syncthreads();

        #pragma unroll
        for (int i = 0; i < 4; ++i) {
            const int r = wid * 32 + i * 8 + st_r;
            const int gsrc = (st_g ^ (r & 7)) << 3;
            const u16* srcA = wsA + (size_t)(m0 + r) * K + k0 + gsrc;
            const u16* srcB = wsW + (size_t)(n0 + r) * K + k0 + gsrc;
            __builtin_amdgcn_global_load_lds(
                (const __attribute__((address_space(1))) void*)srcA,
                (__attribute__((address_space(3))) void*)&sA[(wid * 32 + i * 8) * BK],
                16, 0, 0);
            __builtin_amdgcn_global_load_lds(
                (const __attribute__((address_space(1))) void*)srcB,
                (__attribute__((address_space(3))) void*)&sB[(wid * 32 + i * 8) * BK],
                16, 0, 0);
        }

        __syncthreads();

        #pragma unroll
        for (int sub = 0; sub < 2; ++sub) {
            const int kch = (sub << 2) + fq;
            bf16x8 af[4], bfg[4];
            #pragma unroll
            for (int i = 0; i < 4; ++i) {
                const int row = wr + i * 16 + fr;
                af[i] = *(const bf16x8*)((const char*)sA + row * (BK * 2)
                                         + (((kch ^ (row & 7)) << 4)));
            }
            #pragma unroll
            for (int j = 0; j < 4; ++j) {
                const int row = wc + j * 16 + fr;
                bfg[j] = *(const bf16x8*)((const char*)sB + row * (BK * 2)
                                          + (((kch ^ (row & 7)) << 4)));
            }
            #pragma unroll
            for (int i = 0; i < 4; ++i)
                #pragma unroll
                for (int j = 0; j < 4; ++j)
                    acc[i][j] = __builtin_amdgcn_mfma_f32_16x16x32_bf16(
                        af[i], bfg[j], acc[i][j], 0, 0, 0);
        }
    }

    #pragma unroll
    for (int j = 0; j < 4; ++j) {
        const int n = n0 + wc + j * 16 + fr;
        const float bvv = Bias[n];
        #pragma unroll
        for (int i = 0; i < 4; ++i) {
            const int mb = m0 + wr + i * 16 + (fq << 2);
            #pragma unroll
            for (int r = 0; r < 4; ++r)
                Out[(size_t)(mb + r) * N + n] = acc[i][j][r] + bvv;
        }
    }
}

// ---------------- round-1 fused fallback ----------------

__global__ __launch_bounds__(THREADS, 2)
void gql_gemm(const float* __restrict__ A,
              const int* __restrict__ Wp,
              const float* __restrict__ Ws,
              const float* __restrict__ Wb,
              const float* __restrict__ Bias,
              float* __restrict__ Out,
              int M, int N, int K, int G, int gshift)
{
    __shared__ __align__(16) u16 sA[BM * BK];
    __shared__ __align__(16) u16 sB[BN * BK];

    const int tid  = threadIdx.x;
    const int lane = tid & 63;
    const int wid  = tid >> 6;

    const int nwg = gridDim.x;
    int wg = blockIdx.x;
    if ((nwg & 7) == 0) wg = (wg & 7) * (nwg >> 3) + (wg >> 3);
    const int nt     = N / BN;
    const int m0 = (wg / nt) * BM;
    const int n0 = (wg % nt) * BN;

    const int wpr = K >> 2;

    const int a_r = tid >> 4;
    const int a_c = (tid & 15) << 2;
    const int b_r = tid >> 3;
    const int b_w = (tid & 7) << 1;

    const int wr = (wid >> 1) << 6;
    const int wc = (wid & 1) << 6;
    const int fr = lane & 15;
    const int fq = lane >> 4;

    f32x4 acc[4][4] = {};

    for (int k0 = 0; k0 < K; k0 += BK) {
        __syncthreads();

        #pragma unroll
        for (int it = 0; it < 8; ++it) {
            const int row = it * 16 + a_r;
            const float4 v = *(const float4*)(A + (size_t)(m0 + row) * K + (k0 + a_c));
            u16 h0 = f2bf(v.x), h1 = f2bf(v.y), h2 = f2bf(v.z), h3 = f2bf(v.w);
            const int byte = (a_c << 1) ^ ((row & 7) << 4);
            *(u16*)((char*)sA + row * (BK * 2) + byte + 0) = h0;
            *(u16*)((char*)sA + row * (BK * 2) + byte + 2) = h1;
            *(u16*)((char*)sA + row * (BK * 2) + byte + 4) = h2;
            *(u16*)((char*)sA + row * (BK * 2) + byte + 6) = h3;
        }

        const int g = k0 >> gshift;
        #pragma unroll
        for (int it = 0; it < 4; ++it) {
            const int row = it * 32 + b_r;
            const int gn  = n0 + row;
            const int2 w2 = *(const int2*)(Wp + (size_t)gn * wpr + (k0 >> 2) + b_w);
            const float s = Ws[gn * G + g];
            const float b = Wb[gn * G + g];
            u16x8 h;
            #pragma unroll
            for (int j = 0; j < 4; ++j)
                h[j]     = f2bf(fmaf((float)((w2.x >> (4 * j)) & 0xF), s, b));
            #pragma unroll
            for (int j = 0; j < 4; ++j)
                h[4 + j] = f2bf(fmaf((float)((w2.y >> (4 * j)) & 0xF), s, b));
            const int byte = (b_w << 3) ^ ((row & 7) << 4);
            *(u16x8*)((char*)sB + row * (BK * 2) + byte) = h;
        }

        __syncthreads();

        #pragma unroll
        for (int sub = 0; sub < 2; ++sub) {
            const int kch = (sub << 2) + fq;
            bf16x8 af[4], bfg[4];
            #pragma unroll
            for (int i = 0; i < 4; ++i) {
                const int row = wr + i * 16 + fr;
                af[i] = *(const bf16x8*)((const char*)sA + row * (BK * 2)
                                         + ((kch << 4) ^ ((row & 7) << 4)));
            }
            #pragma unroll
            for (int j = 0; j < 4; ++j) {
                const int row = wc + j * 16 + fr;
                bfg[j] = *(const bf16x8*)((const char*)sB + row * (BK * 2)
                                          + ((kch << 4) ^ ((row & 7) << 4)));
            }
            #pragma unroll
            for (int i = 0; i < 4; ++i)
                #pragma unroll
                for (int j = 0; j < 4; ++j)
                    acc[i][j] = __builtin_amdgcn_mfma_f32_16x16x32_bf16(
                        af[i], bfg[j], acc[i][j], 0, 0, 0);
        }
    }

    #pragma unroll
    for (int j = 0; j < 4; ++j) {
        const int n = n0 + wc + j * 16 + fr;
        const float bvv = Bias[n];
        #pragma unroll
        for (int i = 0; i < 4; ++i) {
            const int mb = m0 + wr + i * 16 + (fq << 2);
            #pragma unroll
            for (int r = 0; r < 4; ++r)
                Out[(size_t)(mb + r) * N + n] = acc[i][j][r] + bvv;
        }
    }
}

extern "C" void kernel_launch(void* const* d_in, const int* in_sizes, int n_in,
                              void* d_out, int out_size, void* d_ws, size_t ws_size,
                              hipStream_t stream) {
    const float* A    = (const float*)d_in[0];
    const int*   Wp   = (const int*)d_in[1];
    const float* Ws   = (const float*)d_in[2];
    const float* Wb   = (const float*)d_in[3];
    const float* Bias = (const float*)d_in[4];
    float* Out = (float*)d_out;

    const int OUT  = in_sizes[4];
    const int OG   = in_sizes[2];          // OUT * G
    const int G    = OG / OUT;             // 16
    const int cols = in_sizes[1] / OG;     // 64
    const int IN   = G * cols * 4;         // 4096
    const int M    = in_sizes[0] / IN;     // 4096

    const int gk = IN / G;                 // 256
    int gshift = 0;
    while ((1 << gshift) < gk) ++gshift;   // 8

    int kshift = 0;
    while ((1 << kshift) < IN) ++kshift;   // 12

    const size_t needXq = (size_t)M * IN;
    const size_t needWq = (size_t)OUT * IN;
    const size_t needSc = (size_t)M * 8 + (size_t)OUT * 8;
    const size_t needI8 = needXq + needWq + needSc;

    const bool kpow2  = ((IN & (IN - 1)) == 0);
    const bool gkpow2 = ((1 << gshift) == gk);

    if (ws_size >= needI8 && kpow2 && gkpow2 && (IN % 256) == 0 &&
        (M % 256) == 0 && (OUT % 256) == 0 && (gk % 16) == 0) {
        char*  xq   = (char*)d_ws;
        char*  wq   = (char*)d_ws + needXq;
        float* sx   = (float*)((char*)d_ws + needXq + needWq);
        float* rsx  = sx + M;
        float* swr  = rsx + M;
        float* rswr = swr + OUT;

        rowstat_kernel<<<M, 64, 0, stream>>>(A, sx, rsx, IN);

        const size_t n16 = (size_t)M * IN / 16;
        quantX_kernel<<<(unsigned)((n16 + 255) / 256), 256, 0, stream>>>(
            A, rsx, xq, kshift, n16);

        rowscaleW_kernel<<<(OUT + 255) / 256, 256, 0, stream>>>(Ws, Wb, swr, rswr,
                                                                G, OUT);

        const int kcshift = kshift - 4;                 // log2(K/16)
        const size_t nthr = (size_t)OUT * (IN >> 4);
        quantW_row_kernel<<<(unsigned)((nthr + 255) / 256), 256, 0, stream>>>(
            Wp, Ws, Wb, rswr, wq, IN, G, gshift, kcshift, nthr);

        dim3 grid((M / 256) * (OUT / 256));
        gql_gemm_i8v<<<grid, 512, 0, stream>>>(xq, wq, swr, sx, Bias, Out,
                                               M, OUT, IN);
        return;
    }

    const size_t needA = (size_t)M * IN * 2;
    const size_t needW = (size_t)OUT * IN * 2;

    if (ws_size >= needA + needW && (IN & 7) == 0 &&
        (M % 128) == 0 && (OUT % 128) == 0 && (IN % 64) == 0) {
        u16* wsA = (u16*)d_ws;
        u16* wsW = (u16*)((char*)d_ws + needA);

        const size_t nA8 = (size_t)M * IN / 8;
        cvtA_kernel<<<(unsigned)((nA8 + 255) / 256), 256, 0, stream>>>(A, wsA, nA8);

        int kgshift = 0;
        while ((1 << kgshift) < (IN >> 3)) ++kgshift;
        const size_t nW8 = (size_t)OUT * IN / 8;
        deqW_kernel<<<(unsigned)((nW8 + 255) / 256), 256, 0, stream>>>(
            Wp, Ws, Wb, wsW, IN, G, gshift, kgshift, nW8);

        dim3 grid((M / BM) * (OUT / BN));
        gql_gemm_pre<<<grid, THREADS, 0, stream>>>(wsA, wsW, Bias, Out, M, OUT, IN);
    } else {
        dim3 grid((M / BM) * (OUT / BN));
        gql_gemm<<<grid, THREADS, 0, stream>>>(A, Wp, Ws, Wb, Bias, Out,
                                               M, OUT, IN, G, gshift);
    }
}

// Round 13
// 352.165 us; speedup vs baseline: 1.1764x; 1.1623x over previous
//
#include <hip/hip_runtime.h>
#include <hip/hip_bf16.h>

// GroupQuantLinear: y[m,n] = sum_k x[m,k]*(q[n,k]*s[n,g]+b[n,g]) + bias[n]
// M=4096, N=16384, K=4096, G=16.
//
// Round 13: consolidation. GEMM = r8's gql_gemm_i8s verbatim (best of 7
// schedule structures: 343us, MfmaUtil 34.5, 0 bank conflicts, absmax
// 0.375). Precompute trimmed: rowstat+quantX fused into one kernel
// (row in registers: one A read instead of two, one dispatch fewer).
// W-side precompute and all fallbacks unchanged (validated).

typedef short bf16x8 __attribute__((ext_vector_type(8)));
typedef float f32x4 __attribute__((ext_vector_type(4)));
typedef int i32x4 __attribute__((ext_vector_type(4)));
typedef unsigned short u16;
typedef unsigned short u16x8 __attribute__((ext_vector_type(8)));

#define BM 128
#define BN 128
#define BK 64
#define THREADS 256

static __device__ __forceinline__ u16 f2bf(float f) {
    __hip_bfloat16 h = __float2bfloat16(f);
    return __builtin_bit_cast(u16, h);
}

// ---------------- i8 precompute ----------------

// Fused row-max + quantize for K == 4096: one 256-thread block per row,
// 16 floats/thread held in registers between the reduce and the quantize.
__global__ __launch_bounds__(256)
void quantX_fused_kernel(const float* __restrict__ x, float* __restrict__ sx,
                         char* __restrict__ xq, int K) {
    const int m   = blockIdx.x;
    const int tid = threadIdx.x;            // 0..255
    const int lane = tid & 63;
    const int wv   = tid >> 6;              // 0..3
    __shared__ float red[4];

    const float4* p = (const float4*)(x + (size_t)m * K);
    float4 v0 = p[tid];
    float4 v1 = p[tid + 256];
    float4 v2 = p[tid + 512];
    float4 v3 = p[tid + 768];

    float mx = 0.f;
    mx = fmaxf(mx, fmaxf(fmaxf(fabsf(v0.x), fabsf(v0.y)), fmaxf(fabsf(v0.z), fabsf(v0.w))));
    mx = fmaxf(mx, fmaxf(fmaxf(fabsf(v1.x), fabsf(v1.y)), fmaxf(fabsf(v1.z), fabsf(v1.w))));
    mx = fmaxf(mx, fmaxf(fmaxf(fabsf(v2.x), fabsf(v2.y)), fmaxf(fabsf(v2.z), fabsf(v2.w))));
    mx = fmaxf(mx, fmaxf(fmaxf(fabsf(v3.x), fabsf(v3.y)), fmaxf(fabsf(v3.z), fabsf(v3.w))));
    #pragma unroll
    for (int o = 32; o; o >>= 1) mx = fmaxf(mx, __shfl_xor(mx, o));
    if (lane == 0) red[wv] = mx;
    __syncthreads();
    mx = fmaxf(fmaxf(red[0], red[1]), fmaxf(red[2], red[3]));
    mx = fmaxf(mx, 1e-20f);
    const float r = 127.f / mx;
    if (tid == 0) sx[m] = mx * (1.f / 127.f);

    int* xo = (int*)(xq + (size_t)m * K);
    {
        const int b = (__float2int_rn(v0.x * r) & 0xFF) | ((__float2int_rn(v0.y * r) & 0xFF) << 8)
                    | ((__float2int_rn(v0.z * r) & 0xFF) << 16) | ((__float2int_rn(v0.w * r) & 0xFF) << 24);
        xo[tid] = b;
    }
    {
        const int b = (__float2int_rn(v1.x * r) & 0xFF) | ((__float2int_rn(v1.y * r) & 0xFF) << 8)
                    | ((__float2int_rn(v1.z * r) & 0xFF) << 16) | ((__float2int_rn(v1.w * r) & 0xFF) << 24);
        xo[tid + 256] = b;
    }
    {
        const int b = (__float2int_rn(v2.x * r) & 0xFF) | ((__float2int_rn(v2.y * r) & 0xFF) << 8)
                    | ((__float2int_rn(v2.z * r) & 0xFF) << 16) | ((__float2int_rn(v2.w * r) & 0xFF) << 24);
        xo[tid + 512] = b;
    }
    {
        const int b = (__float2int_rn(v3.x * r) & 0xFF) | ((__float2int_rn(v3.y * r) & 0xFF) << 8)
                    | ((__float2int_rn(v3.z * r) & 0xFF) << 16) | ((__float2int_rn(v3.w * r) & 0xFF) << 24);
        xo[tid + 768] = b;
    }
}

// general-K fallback pair (r6-r12 validated)
__global__ void rowstat_kernel(const float* __restrict__ x, float* __restrict__ sx,
                               float* __restrict__ rsx, int K) {
    const int m = blockIdx.x;
    const int l = threadIdx.x;  // 64
    const float4* p = (const float4*)(x + (size_t)m * K);
    float mx = 0.f;
    for (int i = l; i < (K >> 2); i += 64) {
        const float4 v = p[i];
        mx = fmaxf(mx, fmaxf(fmaxf(fabsf(v.x), fabsf(v.y)),
                             fmaxf(fabsf(v.z), fabsf(v.w))));
    }
    #pragma unroll
    for (int o = 32; o; o >>= 1) mx = fmaxf(mx, __shfl_xor(mx, o));
    if (l == 0) {
        mx = fmaxf(mx, 1e-20f);
        sx[m]  = mx * (1.f / 127.f);
        rsx[m] = 127.f / mx;
    }
}

__global__ void quantX_kernel(const float* __restrict__ x, const float* __restrict__ rsx,
                              char* __restrict__ xq, int kshift, size_t n16) {
    size_t i = (size_t)blockIdx.x * blockDim.x + threadIdx.x;
    if (i >= n16) return;
    const int m = (int)((i * 16) >> kshift);
    const float r = rsx[m];
    const float4* px = (const float4*)(x + i * 16);
    int out[4];
    #pragma unroll
    for (int w = 0; w < 4; ++w) {
        const float4 v = px[w];
        const int b0 = __float2int_rn(v.x * r) & 0xFF;
        const int b1 = __float2int_rn(v.y * r) & 0xFF;
        const int b2 = __float2int_rn(v.z * r) & 0xFF;
        const int b3 = __float2int_rn(v.w * r) & 0xFF;
        out[w] = b0 | (b1 << 8) | (b2 << 16) | (b3 << 24);
    }
    *(int4*)(xq + i * 16) = make_int4(out[0], out[1], out[2], out[3]);
}

__global__ void rowscaleW_kernel(const float* __restrict__ Ws,
                                 const float* __restrict__ Wb,
                                 float* __restrict__ swr, float* __restrict__ rswr,
                                 int G, int N) {
    const int n = blockIdx.x * blockDim.x + threadIdx.x;
    if (n >= N) return;
    float mx = 1e-20f;
    for (int g = 0; g < G; ++g) {
        const float s = Ws[(size_t)n * G + g];
        const float b = Wb[(size_t)n * G + g];
        mx = fmaxf(mx, fmaxf(fabsf(b), fabsf(fmaf(15.f, s, b))));
    }
    swr[n]  = mx * (1.f / 127.f);
    rswr[n] = 127.f / mx;
}

__global__ void quantW_row_kernel(const int* __restrict__ Wp, const float* __restrict__ Ws,
                                  const float* __restrict__ Wb, const float* __restrict__ rswr,
                                  char* __restrict__ wq, int K, int G, int gshift,
                                  int kcshift, size_t nthr) {
    size_t t = (size_t)blockIdx.x * blockDim.x + threadIdx.x;
    if (t >= nthr) return;
    const int n  = (int)(t >> kcshift);
    const int kc = (int)(t & ((1u << kcshift) - 1));
    const int g  = (kc << 4) >> gshift;
    const float s = Ws[(size_t)n * G + g];
    const float b = Wb[(size_t)n * G + g];
    const float rs = rswr[n];
    const int4 wv = *(const int4*)(Wp + (size_t)n * (K >> 2) + ((size_t)kc << 2));
    const int wds[4] = {wv.x, wv.y, wv.z, wv.w};
    int out[4];
    #pragma unroll
    for (int w = 0; w < 4; ++w) {
        int o = 0;
        #pragma unroll
        for (int j = 0; j < 4; ++j) {
            const float v = fmaf((float)((wds[w] >> (4 * j)) & 0xF), s, b);
            o |= (__float2int_rn(v * rs) & 0xFF) << (8 * j);
        }
        out[w] = o;
    }
    *(int4*)(wq + t * 16) = make_int4(out[0], out[1], out[2], out[3]);
}

// -- i8 GEMM (r8 verbatim): 256x256, 8 waves of 128x64, 16x16x64, BK=128 --

__global__ __launch_bounds__(512, 2)
void gql_gemm_i8s(const char* __restrict__ xq,   // [M][K] i8
                  const char* __restrict__ wq,   // [N][K] i8
                  const float* __restrict__ swr, // [N]
                  const float* __restrict__ sx,  // [M]
                  const float* __restrict__ Bias,
                  float* __restrict__ Out,       // [M][N] f32
                  int M, int N, int K)
{
    __shared__ __align__(16) char sA[2][256 * 128];  // 32 KB each
    __shared__ __align__(16) char sB[2][256 * 128];  // 32 KB each -> 128 KB

    const int tid  = threadIdx.x;
    const int lane = tid & 63;
    const int wid  = tid >> 6;     // 0..7
    const int wm   = wid >> 2;     // 0..1 -> rows wm*128
    const int wn   = wid & 3;      // 0..3 -> cols wn*64

    const int nwg = gridDim.x;
    int wg = blockIdx.x;
    if ((nwg & 7) == 0) wg = (wg & 7) * (nwg >> 3) + (wg >> 3);
    const int nt = N / 256;
    const int m0 = (wg / nt) * 256;
    const int n0 = (wg % nt) * 256;

    const int st_row = lane >> 3;                        // 0..7
    const int st_g   = ((lane & 7) ^ (lane >> 3)) << 4;  // byte offset

    const int fr = lane & 15;   // fragment row lane
    const int fq = lane >> 4;   // 0..3 -> k-chunk

    i32x4 acc[8][4] = {};

    const int NT = K >> 7;  // BK=128

    auto stage = [&](int t, int buf) {
        const size_t k0 = (size_t)t << 7;
        #pragma unroll
        for (int i = 0; i < 4; ++i) {
            const int r = wid * 32 + i * 8 + st_row;
            const char* srcA = xq + (size_t)(m0 + r) * K + k0 + st_g;
            __builtin_amdgcn_global_load_lds(
                (const __attribute__((address_space(1))) void*)srcA,
                (__attribute__((address_space(3))) void*)&sA[buf][(wid * 32 + i * 8) * 128],
                16, 0, 0);
            const char* srcB = wq + (size_t)(n0 + r) * K + k0 + st_g;
            __builtin_amdgcn_global_load_lds(
                (const __attribute__((address_space(1))) void*)srcB,
                (__attribute__((address_space(3))) void*)&sB[buf][(wid * 32 + i * 8) * 128],
                16, 0, 0);
        }
    };

    auto ldsrd = [&](const char* base, int row, int gr) -> i32x4 {
        const u16x8 raw = *(const u16x8*)(base + row * 128 + gr * 16);
        return __builtin_bit_cast(i32x4, raw);
    };

    auto compute = [&](int buf) {
        #pragma unroll
        for (int kk = 0; kk < 2; ++kk) {
            const int gr = (kk * 4 + fq) ^ (fr & 7);
            i32x4 af[8], bfr[4];
            #pragma unroll
            for (int i = 0; i < 8; ++i)
                af[i] = ldsrd(&sA[buf][0], wm * 128 + i * 16 + fr, gr);
            #pragma unroll
            for (int j = 0; j < 4; ++j)
                bfr[j] = ldsrd(&sB[buf][0], wn * 64 + j * 16 + fr, gr);
            __builtin_amdgcn_s_setprio(1);
            #pragma unroll
            for (int i = 0; i < 8; ++i)
                #pragma unroll
                for (int j = 0; j < 4; ++j)
                    acc[i][j] = __builtin_amdgcn_mfma_i32_16x16x64_i8(
                        af[i], bfr[j], acc[i][j], 0, 0, 0);
            __builtin_amdgcn_s_setprio(0);
        }
    };

    stage(0, 0);
    int cur = 0;
    for (int t = 0; t < NT - 1; ++t) {
        stage(t + 1, cur ^ 1);                 // overwrites buf consumed at t-1
        __builtin_amdgcn_sched_barrier(0);
        asm volatile("s_waitcnt vmcnt(8)" ::: "memory");  // tile t landed
        __builtin_amdgcn_s_barrier();
        asm volatile("" ::: "memory");
        compute(cur);
        __builtin_amdgcn_sched_barrier(0);
        asm volatile("" ::: "memory");
        __builtin_amdgcn_s_barrier();          // readers done before overwrite
        asm volatile("" ::: "memory");
        cur ^= 1;
    }
    asm volatile("s_waitcnt vmcnt(0)" ::: "memory");
    __builtin_amdgcn_s_barrier();
    asm volatile("" ::: "memory");
    compute(cur);

    // epilogue: 16x16 C-layout: col = fr, row = 4*fq + reg
    #pragma unroll
    for (int j = 0; j < 4; ++j) {
        const int col = n0 + wn * 64 + j * 16 + fr;
        const float bv = Bias[col];
        const float sv = swr[col];
        #pragma unroll
        for (int i = 0; i < 8; ++i) {
            const int mb = m0 + wm * 128 + i * 16 + (fq << 2);
            #pragma unroll
            for (int r = 0; r < 4; ++r)
                Out[(size_t)(mb + r) * N + col] =
                    fmaf(sx[mb + r] * sv, (float)acc[i][j][r], bv);
        }
    }
}

// ---------------- bf16 predecode kernels (fallback path) ----------------

__global__ void cvtA_kernel(const float* __restrict__ A, u16* __restrict__ wsA,
                            size_t n8) {
    size_t i = (size_t)blockIdx.x * blockDim.x + threadIdx.x;
    if (i >= n8) return;
    const float4 v0 = *(const float4*)(A + i * 8);
    const float4 v1 = *(const float4*)(A + i * 8 + 4);
    u16x8 h;
    h[0] = f2bf(v0.x); h[1] = f2bf(v0.y); h[2] = f2bf(v0.z); h[3] = f2bf(v0.w);
    h[4] = f2bf(v1.x); h[5] = f2bf(v1.y); h[6] = f2bf(v1.z); h[7] = f2bf(v1.w);
    *(u16x8*)(wsA + i * 8) = h;
}

__global__ void deqW_kernel(const int* __restrict__ Wp, const float* __restrict__ Ws,
                            const float* __restrict__ Wb, u16* __restrict__ wsW,
                            int K, int G, int gshift, int kgshift, size_t n8) {
    size_t t = (size_t)blockIdx.x * blockDim.x + threadIdx.x;
    if (t >= n8) return;
    const int n  = (int)(t >> kgshift);
    const int kg = (int)(t & ((1u << kgshift) - 1));
    const int k  = kg << 3;
    const int g  = k >> gshift;
    const float s = Ws[n * G + g];
    const float b = Wb[n * G + g];
    const int2 w2 = *(const int2*)(Wp + (size_t)n * (K >> 2) + (k >> 2));
    u16x8 h;
    #pragma unroll
    for (int j = 0; j < 4; ++j)
        h[j]     = f2bf(fmaf((float)((w2.x >> (4 * j)) & 0xF), s, b));
    #pragma unroll
    for (int j = 0; j < 4; ++j)
        h[4 + j] = f2bf(fmaf((float)((w2.y >> (4 * j)) & 0xF), s, b));
    *(u16x8*)(wsW + ((size_t)n << (kgshift + 3)) + k) = h;
}

__global__ __launch_bounds__(THREADS, 2)
void gql_gemm_pre(const u16* __restrict__ wsA,
                  const u16* __restrict__ wsW,
                  const float* __restrict__ Bias,
                  float* __restrict__ Out,
                  int M, int N, int K)
{
    __shared__ __align__(16) u16 sA[BM * BK];
    __shared__ __align__(16) u16 sB[BN * BK];

    const int tid  = threadIdx.x;
    const int lane = tid & 63;
    const int wid  = tid >> 6;

    const int nwg = gridDim.x;
    int wg = blockIdx.x;
    if ((nwg & 7) == 0) wg = (wg & 7) * (nwg >> 3) + (wg >> 3);
    const int nt     = N / BN;
    const int m0 = (wg / nt) * BM;
    const int n0 = (wg % nt) * BN;

    const int st_r  = (lane >> 3);
    const int st_g  = lane & 7;

    const int wr = (wid >> 1) << 6;
    const int wc = (wid & 1) << 6;
    const int fr = lane & 15;
    const int fq = lane >> 4;

    f32x4 acc[4][4] = {};

    for (int k0 = 0; k0 < K; k0 += BK) {
        __syncthreads();

        #pragma unroll
        for (int i = 0; i < 4; ++i) {
            const int r = wid * 32 + i * 8 + st_r;
            const int gsrc = (st_g ^ (r & 7)) << 3;
            const u16* srcA = wsA + (size_t)(m0 + r) * K + k0 + gsrc;
            const u16* srcB = wsW + (size_t)(n0 + r) * K + k0 + gsrc;
            __builtin_amdgcn_global_load_lds(
                (const __attribute__((address_space(1))) void*)srcA,
                (__attribute__((address_space(3))) void*)&sA[(wid * 32 + i * 8) * BK],
                16, 0, 0);
            __builtin_amdgcn_global_load_lds(
                (const __attribute__((address_space(1))) void*)srcB,
                (__attribute__((address_space(3))) void*)&sB[(wid * 32 + i * 8) * BK],
                16, 0, 0);
        }

        __syncthreads();

        #pragma unroll
        for (int sub = 0; sub < 2; ++sub) {
            const int kch = (sub << 2) + fq;
            bf16x8 af[4], bfg[4];
            #pragma unroll
            for (int i = 0; i < 4; ++i) {
                const int row = wr + i * 16 + fr;
                af[i] = *(const bf16x8*)((const char*)sA + row * (BK * 2)
                                         + (((kch ^ (row & 7)) << 4)));
            }
            #pragma unroll
            for (int j = 0; j < 4; ++j) {
                const int row = wc + j * 16 + fr;
                bfg[j] = *(const bf16x8*)((const char*)sB + row * (BK * 2)
                                          + (((kch ^ (row & 7)) << 4)));
            }
            #pragma unroll
            for (int i = 0; i < 4; ++i)
                #pragma unroll
                for (int j = 0; j < 4; ++j)
                    acc[i][j] = __builtin_amdgcn_mfma_f32_16x16x32_bf16(
                        af[i], bfg[j], acc[i][j], 0, 0, 0);
        }
    }

    #pragma unroll
    for (int j = 0; j < 4; ++j) {
        const int n = n0 + wc + j * 16 + fr;
        const float bvv = Bias[n];
        #pragma unroll
        for (int i = 0; i < 4; ++i) {
            const int mb = m0 + wr + i * 16 + (fq << 2);
            #pragma unroll
            for (int r = 0; r < 4; ++r)
                Out[(size_t)(mb + r) * N + n] = acc[i][j][r] + bvv;
        }
    }
}

// ---------------- round-1 fused fallback ----------------

__global__ __launch_bounds__(THREADS, 2)
void gql_gemm(const float* __restrict__ A,
              const int* __restrict__ Wp,
              const float* __restrict__ Ws,
              const float* __restrict__ Wb,
              const float* __restrict__ Bias,
              float* __restrict__ Out,
              int M, int N, int K, int G, int gshift)
{
    __shared__ __align__(16) u16 sA[BM * BK];
    __shared__ __align__(16) u16 sB[BN * BK];

    const int tid  = threadIdx.x;
    const int lane = tid & 63;
    const int wid  = tid >> 6;

    const int nwg = gridDim.x;
    int wg = blockIdx.x;
    if ((nwg & 7) == 0) wg = (wg & 7) * (nwg >> 3) + (wg >> 3);
    const int nt     = N / BN;
    const int m0 = (wg / nt) * BM;
    const int n0 = (wg % nt) * BN;

    const int wpr = K >> 2;

    const int a_r = tid >> 4;
    const int a_c = (tid & 15) << 2;
    const int b_r = tid >> 3;
    const int b_w = (tid & 7) << 1;

    const int wr = (wid >> 1) << 6;
    const int wc = (wid & 1) << 6;
    const int fr = lane & 15;
    const int fq = lane >> 4;

    f32x4 acc[4][4] = {};

    for (int k0 = 0; k0 < K; k0 += BK) {
        __syncthreads();

        #pragma unroll
        for (int it = 0; it < 8; ++it) {
            const int row = it * 16 + a_r;
            const float4 v = *(const float4*)(A + (size_t)(m0 + row) * K + (k0 + a_c));
            u16 h0 = f2bf(v.x), h1 = f2bf(v.y), h2 = f2bf(v.z), h3 = f2bf(v.w);
            const int byte = (a_c << 1) ^ ((row & 7) << 4);
            *(u16*)((char*)sA + row * (BK * 2) + byte + 0) = h0;
            *(u16*)((char*)sA + row * (BK * 2) + byte + 2) = h1;
            *(u16*)((char*)sA + row * (BK * 2) + byte + 4) = h2;
            *(u16*)((char*)sA + row * (BK * 2) + byte + 6) = h3;
        }

        const int g = k0 >> gshift;
        #pragma unroll
        for (int it = 0; it < 4; ++it) {
            const int row = it * 32 + b_r;
            const int gn  = n0 + row;
            const int2 w2 = *(const int2*)(Wp + (size_t)gn * wpr + (k0 >> 2) + b_w);
            const float s = Ws[gn * G + g];
            const float b = Wb[gn * G + g];
            u16x8 h;
            #pragma unroll
            for (int j = 0; j < 4; ++j)
                h[j]     = f2bf(fmaf((float)((w2.x >> (4 * j)) & 0xF), s, b));
            #pragma unroll
            for (int j = 0; j < 4; ++j)
                h[4 + j] = f2bf(fmaf((float)((w2.y >> (4 * j)) & 0xF), s, b));
            const int byte = (b_w << 3) ^ ((row & 7) << 4);
            *(u16x8*)((char*)sB + row * (BK * 2) + byte) = h;
        }

        __syncthreads();

        #pragma unroll
        for (int sub = 0; sub < 2; ++sub) {
            const int kch = (sub << 2) + fq;
            bf16x8 af[4], bfg[4];
            #pragma unroll
            for (int i = 0; i < 4; ++i) {
                const int row = wr + i * 16 + fr;
                af[i] = *(const bf16x8*)((const char*)sA + row * (BK * 2)
                                         + ((kch << 4) ^ ((row & 7) << 4)));
            }
            #pragma unroll
            for (int j = 0; j < 4; ++j) {
                const int row = wc + j * 16 + fr;
                bfg[j] = *(const bf16x8*)((const char*)sB + row * (BK * 2)
                                          + ((kch << 4) ^ ((row & 7) << 4)));
            }
            #pragma unroll
            for (int i = 0; i < 4; ++i)
                #pragma unroll
                for (int j = 0; j < 4; ++j)
                    acc[i][j] = __builtin_amdgcn_mfma_f32_16x16x32_bf16(
                        af[i], bfg[j], acc[i][j], 0, 0, 0);
        }
    }

    #pragma unroll
    for (int j = 0; j < 4; ++j) {
        const int n = n0 + wc + j * 16 + fr;
        const float bvv = Bias[n];
        #pragma unroll
        for (int i = 0; i < 4; ++i) {
            const int mb = m0 + wr + i * 16 + (fq << 2);
            #pragma unroll
            for (int r = 0; r < 4; ++r)
                Out[(size_t)(mb + r) * N + n] = acc[i][j][r] + bvv;
        }
    }
}

extern "C" void kernel_launch(void* const* d_in, const int* in_sizes, int n_in,
                              void* d_out, int out_size, void* d_ws, size_t ws_size,
                              hipStream_t stream) {
    const float* A    = (const float*)d_in[0];
    const int*   Wp   = (const int*)d_in[1];
    const float* Ws   = (const float*)d_in[2];
    const float* Wb   = (const float*)d_in[3];
    const float* Bias = (const float*)d_in[4];
    float* Out = (float*)d_out;

    const int OUT  = in_sizes[4];
    const int OG   = in_sizes[2];          // OUT * G
    const int G    = OG / OUT;             // 16
    const int cols = in_sizes[1] / OG;     // 64
    const int IN   = G * cols * 4;         // 4096
    const int M    = in_sizes[0] / IN;     // 4096

    const int gk = IN / G;                 // 256
    int gshift = 0;
    while ((1 << gshift) < gk) ++gshift;   // 8

    int kshift = 0;
    while ((1 << kshift) < IN) ++kshift;   // 12

    const size_t needXq = (size_t)M * IN;
    const size_t needWq = (size_t)OUT * IN;
    const size_t needSc = (size_t)M * 8 + (size_t)OUT * 8;
    const size_t needI8 = needXq + needWq + needSc;

    const bool kpow2  = ((IN & (IN - 1)) == 0);
    const bool gkpow2 = ((1 << gshift) == gk);

    if (ws_size >= needI8 && kpow2 && gkpow2 && (IN % 256) == 0 && IN >= 256 &&
        (M % 256) == 0 && (OUT % 256) == 0 && (gk % 16) == 0) {
        char*  xq   = (char*)d_ws;
        char*  wq   = (char*)d_ws + needXq;
        float* sx   = (float*)((char*)d_ws + needXq + needWq);
        float* rsx  = sx + M;
        float* swr  = rsx + M;
        float* rswr = swr + OUT;

        if (IN == 4096) {
            quantX_fused_kernel<<<M, 256, 0, stream>>>(A, sx, xq, IN);
        } else {
            rowstat_kernel<<<M, 64, 0, stream>>>(A, sx, rsx, IN);
            const size_t n16 = (size_t)M * IN / 16;
            quantX_kernel<<<(unsigned)((n16 + 255) / 256), 256, 0, stream>>>(
                A, rsx, xq, kshift, n16);
        }

        rowscaleW_kernel<<<(OUT + 255) / 256, 256, 0, stream>>>(Ws, Wb, swr, rswr,
                                                                G, OUT);

        const int kcshift = kshift - 4;                 // log2(K/16)
        const size_t nthr = (size_t)OUT * (IN >> 4);
        quantW_row_kernel<<<(unsigned)((nthr + 255) / 256), 256, 0, stream>>>(
            Wp, Ws, Wb, rswr, wq, IN, G, gshift, kcshift, nthr);

        dim3 grid((M / 256) * (OUT / 256));
        gql_gemm_i8s<<<grid, 512, 0, stream>>>(xq, wq, swr, sx, Bias, Out,
                                               M, OUT, IN);
        return;
    }

    const size_t needA = (size_t)M * IN * 2;
    const size_t needW = (size_t)OUT * IN * 2;

    if (ws_size >= needA + needW && (IN & 7) == 0 &&
        (M % 128) == 0 && (OUT % 128) == 0 && (IN % 64) == 0) {
        u16* wsA = (u16*)d_ws;
        u16* wsW = (u16*)((char*)d_ws + needA);

        const size_t nA8 = (size_t)M * IN / 8;
        cvtA_kernel<<<(unsigned)((nA8 + 255) / 256), 256, 0, stream>>>(A, wsA, nA8);

        int kgshift = 0;
        while ((1 << kgshift) < (IN >> 3)) ++kgshift;
        const size_t nW8 = (size_t)OUT * IN / 8;
        deqW_kernel<<<(unsigned)((nW8 + 255) / 256), 256, 0, stream>>>(
            Wp, Ws, Wb, wsW, IN, G, gshift, kgshift, nW8);

        dim3 grid((M / BM) * (OUT / BN));
        gql_gemm_pre<<<grid, THREADS, 0, stream>>>(wsA, wsW, Bias, Out, M, OUT, IN);
    } else {
        dim3 grid((M / BM) * (OUT / BN));
        gql_gemm<<<grid, THREADS, 0, stream>>>(A, Wp, Ws, Wb, Bias, Out,
                                               M, OUT, IN, G, gshift);
    }
}